// Round 6
// baseline (136.907 us; speedup 1.0000x reference)
//
#include <hip/hip_runtime.h>
#include <math.h>

#define BB   512
#define TT   256
#define EMBD 364
#define HS   64
#define KPAD 384
#define NC   192

typedef __attribute__((ext_vector_type(8))) short short8_t;  // 8 bf16
typedef __attribute__((ext_vector_type(4))) float f32x4;

__device__ __forceinline__ ushort f2bf(float v) {
    union { float f; unsigned u; } c; c.f = v;
    unsigned b = c.u;
    return (ushort)((b + 0x7FFF + ((b >> 16) & 1)) >> 16);   // RNE
}

// ---------------- d_ws layout (bytes) ----------------
#define WTR_BYTES ((size_t)144 * 512 * 2)            // 147456 (B-frag-ordered W)
#define KQ_ELEMS  ((size_t)BB * TT * HS)             // 8388608
#define K_OFF_B   (WTR_BYTES)
#define Q_OFF_B   (K_OFF_B + KQ_ELEMS * 2)
#define VT_OFF_B  (Q_OFF_B + KQ_ELEMS * 2)

// ---------- kernel 0: W -> B-fragment-ordered bf16 WTr, k-part pre-scaled ----------
// slot (jj, t): jj = N-tile (16 cols of [k|q|v]), t = K-subchunk (32). 512 ushorts:
// lane l (64) x elem i (8): value = W^T[col = jj*16 + (l&15)][k = t*32 + (l>>4)*8 + i]
__global__ void prep_wtr(const float* __restrict__ Wk, const float* __restrict__ Wq,
                         const float* __restrict__ Wv, ushort* __restrict__ WTr)
{
    const int bid = blockIdx.x;          // 0..143 = jj*12 + t
    const int jj  = bid / 12;
    const int t   = bid % 12;
    const int l   = threadIdx.x;
    const int c   = jj * 16 + (l & 15);
    const float* Wp = (c < 64) ? Wk : (c < 128 ? Wq : Wv);
    const float s   = (c < 64) ? 0.125f : 1.0f;
    const int col   = c & 63;
    #pragma unroll
    for (int i = 0; i < 8; ++i) {
        int k = t * 32 + (l >> 4) * 8 + i;
        float v = (k < EMBD) ? Wp[(size_t)k * HS + col] * s : 0.f;
        WTr[((size_t)bid * 64 + l) * 8 + i] = f2bf(v);
    }
}

// ================= Kernel A: barrier-free projection GEMM, register-B =================
// 2048 blocks x 256 thr (4 waves). Wave w: N-group w (48 cols), 4 M-tiles of 16 rows.
// No __syncthreads anywhere. x: coalesced 2-deep prefetch -> wave-private LDS bounce.
__global__ __launch_bounds__(256, 2) void proj_gemm(
    const float* __restrict__ x, const ushort* __restrict__ WTr,
    const float* __restrict__ bk_, const float* __restrict__ bq_,
    const float* __restrict__ bv_,
    ushort* __restrict__ Kg, ushort* __restrict__ Qg, ushort* __restrict__ Vt)
{
    const int blk = blockIdx.x;
    const int tid = threadIdx.x;
    const int l   = tid & 63;
    const int w   = tid >> 6;
    const int l15 = l & 15;
    const int lg  = l >> 4;
    const int srow = l >> 2;            // 0..15  (staging row within M-tile)
    const int scg  = l & 3;             // 16-float column group

    __shared__ ushort xs_all[4][16 * 72];
    ushort* xs = xs_all[w];

    const float* xb = x + (size_t)blk * 64 * EMBD;

    // ---- preload B fragments: 3 j-tiles x 12 k-subchunks, coalesced 1KB each ----
    short8_t Bf[3][12];
    #pragma unroll
    for (int j = 0; j < 3; ++j)
        #pragma unroll
        for (int t = 0; t < 12; ++t)
            Bf[j][t] = *(const short8_t*)&WTr[(((size_t)(w * 3 + j) * 12 + t) * 64 + l) * 8];

    float bias3[3];
    #pragma unroll
    for (int j = 0; j < 3; ++j) {
        int c = w * 48 + j * 16 + l15;
        bias3[j] = (c < 64) ? bk_[c] * 0.125f : (c < 128 ? bq_[c - 64] : bv_[c - 128]);
    }

    float sA[16], sB[16];

    // LOAD chunk (mt, kc) into s[16]: lane reads 64B contiguous of row srow
    auto LOADC = [&](int mt, int kc, float* s) {
        const float* base = &xb[(size_t)(mt * 16 + srow) * EMBD + kc * 64 + scg * 16];
        if (kc < 5) {
            #pragma unroll
            for (int u = 0; u < 4; ++u) {
                float4 f = *(const float4*)(base + u * 4);
                s[u * 4 + 0] = f.x; s[u * 4 + 1] = f.y;
                s[u * 4 + 2] = f.z; s[u * 4 + 3] = f.w;
            }
        } else {
            // cols 320 + scg*16 + [0,16): mask past 364
            if (scg < 2) {
                #pragma unroll
                for (int u = 0; u < 4; ++u) {
                    float4 f = *(const float4*)(base + u * 4);
                    s[u * 4 + 0] = f.x; s[u * 4 + 1] = f.y;
                    s[u * 4 + 2] = f.z; s[u * 4 + 3] = f.w;
                }
            } else if (scg == 2) {
                #pragma unroll
                for (int u = 0; u < 3; ++u) {
                    float4 f = *(const float4*)(base + u * 4);
                    s[u * 4 + 0] = f.x; s[u * 4 + 1] = f.y;
                    s[u * 4 + 2] = f.z; s[u * 4 + 3] = f.w;
                }
                #pragma unroll
                for (int u = 12; u < 16; ++u) s[u] = 0.f;
            } else {
                #pragma unroll
                for (int u = 0; u < 16; ++u) s[u] = 0.f;
            }
        }
    };
    auto WRITEC = [&](const float* s) {
        union { short8_t s8; ushort u[8]; } p0, p1;
        #pragma unroll
        for (int u = 0; u < 8; ++u) { p0.u[u] = f2bf(s[u]); p1.u[u] = f2bf(s[8 + u]); }
        *(short8_t*)&xs[srow * 72 + scg * 16]     = p0.s8;
        *(short8_t*)&xs[srow * 72 + scg * 16 + 8] = p1.s8;
    };

    LOADC(0, 0, sA);
    LOADC(0, 1, sB);

    for (int mt = 0; mt < 4; ++mt) {
        f32x4 acc[3];
        #pragma unroll
        for (int j = 0; j < 3; ++j) acc[j] = (f32x4){0.f, 0.f, 0.f, 0.f};

        #pragma unroll
        for (int kc = 0; kc < 6; ++kc) {
            float* cur = (kc & 1) ? sB : sA;   // u = mt*6+kc, 6 even -> parity = kc
            WRITEC(cur);
            // prefetch 2 chunks ahead (static target since kc is unrolled)
            if (kc < 4)      LOADC(mt, kc + 2, cur);
            else if (mt < 3) LOADC(mt + 1, kc - 4, cur);
            short8_t a0 = *(const short8_t*)&xs[l15 * 72 + 0  + lg * 8];
            short8_t a1 = *(const short8_t*)&xs[l15 * 72 + 32 + lg * 8];
            #pragma unroll
            for (int j = 0; j < 3; ++j) {
                acc[j] = __builtin_amdgcn_mfma_f32_16x16x32_bf16(a0, Bf[j][kc * 2],     acc[j], 0, 0, 0);
                acc[j] = __builtin_amdgcn_mfma_f32_16x16x32_bf16(a1, Bf[j][kc * 2 + 1], acc[j], 0, 0, 0);
            }
        }

        // ---- epilogue for this M-tile: +bias, K/Q row-major, V transposed ----
        const int b   = blk >> 2;
        const int tl0 = (blk & 3) * 64 + mt * 16;
        #pragma unroll
        for (int j = 0; j < 3; ++j) {
            const int c = w * 48 + j * 16 + l15;
            #pragma unroll
            for (int r = 0; r < 4; ++r) {
                const size_t trow = (size_t)blk * 64 + mt * 16 + lg * 4 + r;
                float val = acc[j][r] + bias3[j];
                if (c < 64)       Kg[trow * HS + c]          = f2bf(val);
                else if (c < 128) Qg[trow * HS + (c - 64)]   = f2bf(val);
            }
            if (c >= 128) {
                ushort4 pk;
                pk.x = f2bf(acc[j][0] + bias3[j]);
                pk.y = f2bf(acc[j][1] + bias3[j]);
                pk.z = f2bf(acc[j][2] + bias3[j]);
                pk.w = f2bf(acc[j][3] + bias3[j]);
                *(ushort4*)&Vt[((size_t)b * HS + (c - 128)) * TT + tl0 + lg * 4] = pk;
            }
        }
    }
}

// ================= Kernel B: per-batch causal flash attention, no barriers =================
__global__ __launch_bounds__(512, 4) void attn_fused(
    const ushort* __restrict__ Kg, const ushort* __restrict__ Qg,
    const ushort* __restrict__ Vt, float* __restrict__ out)
{
    const int b   = blockIdx.x;
    const int tid = threadIdx.x;
    const int l   = tid & 63;
    const int w   = tid >> 6;
    const int l15 = l & 15;
    const int lg  = l >> 4;

    __shared__ ushort pb[8][16 * 40];
    ushort* pbw = pb[w];

    const ushort* Kb = Kg + (size_t)b * TT * HS;
    const ushort* Qb = Qg + (size_t)b * TT * HS;
    const ushort* Vb = Vt + (size_t)b * HS * TT;

    #pragma unroll
    for (int half = 0; half < 2; ++half) {
        const int rt = half ? (15 - w) : w;     // balanced causal work: 9 chunks/wave
        const int t0 = rt * 16;

        short8_t afr[2];
        afr[0] = *(const short8_t*)&Kb[(t0 + l15) * HS + lg * 8];
        afr[1] = *(const short8_t*)&Kb[(t0 + l15) * HS + 32 + lg * 8];

        float mr[4], lr[4];
        f32x4 o[4];
        #pragma unroll
        for (int r = 0; r < 4; ++r) { mr[r] = -INFINITY; lr[r] = 0.f; }
        #pragma unroll
        for (int nt = 0; nt < 4; ++nt) o[nt] = (f32x4){0.f, 0.f, 0.f, 0.f};

        const int jd = t0 >> 5;
        for (int j = 0; j <= jd; ++j) {
            const int sb = j * 32;
            f32x4 sacc[2];
            sacc[0] = (f32x4){0.f, 0.f, 0.f, 0.f};
            sacc[1] = (f32x4){0.f, 0.f, 0.f, 0.f};
            #pragma unroll
            for (int kk = 0; kk < 2; ++kk) {
                #pragma unroll
                for (int ct = 0; ct < 2; ++ct) {
                    short8_t bfr = *(const short8_t*)&Qb[(sb + ct * 16 + l15) * HS + kk * 32 + lg * 8];
                    sacc[ct] = __builtin_amdgcn_mfma_f32_16x16x32_bf16(afr[kk], bfr, sacc[ct], 0, 0, 0);
                }
            }
            #pragma unroll
            for (int ct = 0; ct < 2; ++ct) {
                int s = sb + ct * 16 + l15;
                #pragma unroll
                for (int r = 0; r < 4; ++r) {
                    int t = t0 + lg * 4 + r;
                    if (s > t) sacc[ct][r] = -INFINITY;
                }
            }
            float p0[4], p1[4], fsc[4];
            #pragma unroll
            for (int r = 0; r < 4; ++r) {
                float mx = fmaxf(sacc[0][r], sacc[1][r]);
                mx = fmaxf(mx, __shfl_xor(mx, 1));
                mx = fmaxf(mx, __shfl_xor(mx, 2));
                mx = fmaxf(mx, __shfl_xor(mx, 4));
                mx = fmaxf(mx, __shfl_xor(mx, 8));
                float nm = fmaxf(mr[r], mx);
                fsc[r] = __expf(mr[r] - nm);
                mr[r] = nm;
                p0[r] = __expf(sacc[0][r] - nm);
                p1[r] = __expf(sacc[1][r] - nm);
                float ps = p0[r] + p1[r];
                ps += __shfl_xor(ps, 1);
                ps += __shfl_xor(ps, 2);
                ps += __shfl_xor(ps, 4);
                ps += __shfl_xor(ps, 8);
                lr[r] = lr[r] * fsc[r] + ps;
            }
            #pragma unroll
            for (int nt = 0; nt < 4; ++nt)
                #pragma unroll
                for (int r = 0; r < 4; ++r) o[nt][r] *= fsc[r];
            #pragma unroll
            for (int r = 0; r < 4; ++r) {
                pbw[(lg * 4 + r) * 40 + l15]      = f2bf(p0[r]);
                pbw[(lg * 4 + r) * 40 + 16 + l15] = f2bf(p1[r]);
            }
            short8_t pa = *(const short8_t*)&pbw[l15 * 40 + lg * 8];
            #pragma unroll
            for (int nt = 0; nt < 4; ++nt) {
                short8_t bfr = *(const short8_t*)&Vb[(nt * 16 + l15) * TT + sb + lg * 8];
                o[nt] = __builtin_amdgcn_mfma_f32_16x16x32_bf16(pa, bfr, o[nt], 0, 0, 0);
            }
        }
        #pragma unroll
        for (int r = 0; r < 4; ++r) {
            float inv = 1.0f / lr[r];
            int t = t0 + lg * 4 + r;
            float* op = out + ((size_t)b * TT + t) * HS;
            #pragma unroll
            for (int nt = 0; nt < 4; ++nt)
                op[nt * 16 + l15] = o[nt][r] * inv;
        }
    }
}

extern "C" void kernel_launch(void* const* d_in, const int* in_sizes, int n_in,
                              void* d_out, int out_size, void* d_ws, size_t ws_size,
                              hipStream_t stream) {
    const float* x  = (const float*)d_in[0];
    const float* Wk = (const float*)d_in[1];
    const float* bk = (const float*)d_in[2];
    const float* Wq = (const float*)d_in[3];
    const float* bq = (const float*)d_in[4];
    const float* Wv = (const float*)d_in[5];
    const float* bv = (const float*)d_in[6];
    float* out = (float*)d_out;

    ushort* WTr = (ushort*)d_ws;
    ushort* Kg  = (ushort*)((char*)d_ws + K_OFF_B);
    ushort* Qg  = (ushort*)((char*)d_ws + Q_OFF_B);
    ushort* Vt  = (ushort*)((char*)d_ws + VT_OFF_B);

    prep_wtr<<<dim3(144), dim3(64), 0, stream>>>(Wk, Wq, Wv, WTr);
    proj_gemm<<<dim3(2048), dim3(256), 0, stream>>>(x, WTr, bk, bq, bv, Kg, Qg, Vt);
    attn_fused<<<dim3(BB), dim3(512), 0, stream>>>(Kg, Qg, Vt, out);
}